// Round 4
// baseline (498.586 us; speedup 1.0000x reference)
//
#include <hip/hip_runtime.h>
#include <stdint.h>

typedef __attribute__((ext_vector_type(8))) short bf16x8;
typedef __attribute__((ext_vector_type(4))) short bf16x4;
typedef __attribute__((ext_vector_type(4))) float f32x4;

__device__ __forceinline__ unsigned short f2bf(float f) {
  union { float f; unsigned u; } v; v.f = f;
  unsigned u = v.u;
  u += 0x7fffu + ((u >> 16) & 1u);
  return (unsigned short)(u >> 16);
}
__device__ __forceinline__ float bfpk_lo(unsigned pk) {
  union { unsigned u; float f; } v; v.u = pk << 16; return v.f;
}
__device__ __forceinline__ float bfpk_hi(unsigned pk) {
  union { unsigned u; float f; } v; v.u = pk & 0xffff0000u; return v.f;
}

// B-fragment swizzle for mfma_f32_16x16x32_bf16:
// element B[k][n] lives at (((k>>5)*16 + (n>>4))*64 + (((k>>3)&3)*16 + (n&15)))*8 + (k&7)
__device__ __forceinline__ int swz_idx(int k, int n) {
  return ((((k >> 5) * 16 + (n >> 4)) * 64) + (((k >> 3) & 3) * 16 + (n & 15))) * 8 + (k & 7);
}

// stage row stride in bf16 elems: 268 -> 134 words; 134 mod 32 = 6 -> write banks fully
// spread (<=2-way, free); 8B-aligned b64 reads stay bank-uniform. 264 had 4-way write conflicts.
#define ST_STRIDE 268

// ---- module-scope scratch; fully rewritten every call ----
__device__ __attribute__((aligned(16))) unsigned short g_Acswz[65536];
__device__ __attribute__((aligned(16))) unsigned short g_Gswz[65536];
__device__ __attribute__((aligned(16))) unsigned short g_W3swz[65536];

// ---------------- fused prep: zero out + build all three swizzled matrices ----------------
__global__ void prep_all(const float* __restrict__ A, const float* __restrict__ Dw,
                         const float* __restrict__ Ww, float* __restrict__ out) {
  __shared__ float red[256];
  const int b = blockIdx.x;
  const int tid = threadIdx.x;
  out[b * 256 + tid] = 0.f;  // 768*256 == out_size exactly

  if (b < 256) {
    // feature f = b: rowmean via block reduction, then Ac column
    float s = 0.f;
    for (int c = tid; c < 243; c += 256) s += A[b * 243 + c];
    red[tid] = s;
    __syncthreads();
    for (int off = 128; off; off >>= 1) {
      if (tid < off) red[tid] += red[tid + off];
      __syncthreads();
    }
    float rm = red[0] * (1.f / 243.f);
    int k = tid;
    float v = 0.f;
    if (k < 243) {
      int rw = k / 9, j = k - rw * 9;
      int i = rw / 3, c = rw - i * 3;
      int corig = c * 81 + i * 9 + j;
      v = A[b * 243 + corig] - rm;
    }
    g_Acswz[swz_idx(k, b)] = f2bf(v);
  } else if (b < 512) {
    // G2 = I - (A@Dw)^T : B[k=fp][n=f]
    int f = b - 256, fp = tid;
    float s = 0.f;
    for (int c = 0; c < 243; ++c) s += A[f * 243 + c] * Dw[c * 256 + fp];
    g_Gswz[swz_idx(fp, f)] = f2bf(((f == fp) ? 1.f : 0.f) - s);
  } else {
    // W3: B[k=f][n=cc]
    int cc = b - 512, f = tid;
    float v = 0.f;
    if (cc < 243) {
      int rw = cc / 9, j = cc - rw * 9;
      int i = rw / 3, c = rw - i * 3;
      int corig = c * 81 + i * 9 + j;
      v = Ww[corig * 256 + f];
    }
    g_W3swz[swz_idx(f, cc)] = f2bf(v);
  }
}

// ---------------- GEMM core: acc[t][un] (+)= stage(64xK) @ B(Kx64-slice) ----------------
// CMODE 0: C-init = 0 at s==0; CMODE 1: C-init = unpacked lin at s==0.
template <int CMODE>
__device__ __forceinline__ void run_gemm(const unsigned short* __restrict__ Bsrc,
                                         const unsigned short* stg, int w, int lane,
                                         int m, int q, f32x4 (&acc)[4][4],
                                         unsigned (*linpk)[4][2]) {
  bf16x8 bcur[4];
#pragma unroll
  for (int un = 0; un < 4; ++un)
    bcur[un] = *(const bf16x8*)(Bsrc + (((4 * w + un) * 64 + lane) << 3));
#pragma unroll
  for (int s = 0; s < 8; ++s) {
    bf16x8 bnext[4];
    if (s < 7) {
#pragma unroll
      for (int un = 0; un < 4; ++un)
        bnext[un] = *(const bf16x8*)(Bsrc + ((((s + 1) * 16 + 4 * w + un) * 64 + lane) << 3));
    }
    bf16x8 afr[4];
#pragma unroll
    for (int t = 0; t < 4; ++t) {
      const unsigned short* ap = stg + (t * 16 + m) * ST_STRIDE + s * 32 + q * 8;
      bf16x4 lo = *(const bf16x4*)(ap);
      bf16x4 hi = *(const bf16x4*)(ap + 4);
      afr[t] = __builtin_shufflevector(lo, hi, 0, 1, 2, 3, 4, 5, 6, 7);
    }
#pragma unroll
    for (int t = 0; t < 4; ++t)
#pragma unroll
      for (int un = 0; un < 4; ++un) {
        f32x4 cin;
        if (s == 0) {
          if (CMODE == 1) {
            cin[0] = bfpk_lo(linpk[t][un][0]);
            cin[1] = bfpk_hi(linpk[t][un][0]);
            cin[2] = bfpk_lo(linpk[t][un][1]);
            cin[3] = bfpk_hi(linpk[t][un][1]);
          } else {
            cin = (f32x4){0.f, 0.f, 0.f, 0.f};
          }
        } else {
          cin = acc[t][un];
        }
        acc[t][un] = __builtin_amdgcn_mfma_f32_16x16x32_bf16(afr[t], bcur[un], cin, 0, 0, 0);
      }
    if (s < 7) {
#pragma unroll
      for (int un = 0; un < 4; ++un) bcur[un] = bnext[un];
    }
  }
}

// ---------------- main fused kernel ----------------
// 900 blocks = 4 images * 15*15 tiles of 8x8 positions; 4 waves split 256 features.
__global__ __launch_bounds__(256, 3) void lista_fused(
    const float* __restrict__ I, const float* __restrict__ lmb, float* __restrict__ out) {
  __shared__ float img[3][16][16];
  __shared__ __attribute__((aligned(16))) unsigned short stage[64 * ST_STRIDE];
  __shared__ float meanv[64];
  __shared__ float outacc[768];
  __shared__ float lmbs[12 * 256];

  const int tid = threadIdx.x;
  const int lane = tid & 63;
  const int w = tid >> 6;
  const int m = lane & 15;
  const int q = lane >> 4;

  const int blk = blockIdx.x;
  const int b = blk / 225;
  const int t2 = blk - b * 225;
  const int ty = t2 / 15;
  const int tx = t2 - ty * 15;
  const int py0 = ty * 8, px0 = tx * 8;

  const float* Ib = I + b * (3 * 128 * 128);
  for (int r = tid; r < 768; r += 256) {
    int c = r >> 8;
    int yx = r & 255;
    int y = yx >> 4, x = yx & 15;
    img[c][y][x] = Ib[c * 16384 + (py0 + y) * 128 + (px0 + x)];
    outacc[r] = 0.f;
  }
  for (int r = tid; r < 12 * 256; r += 256) lmbs[r] = lmb[r];
  if (tid < 64) meanv[tid] = 0.f;
  __syncthreads();

  // ---- build patch stage (k-order k=(i*3+c)*9+j) + per-position means ----
  {
    const int pos = tid & 63;
    const int part = tid >> 6;
    const int y = pos >> 3, x = pos & 7;
    int j = part, c = 0, i = 0;  // decode of k=part (part<4 -> j=part)
    float s = 0.f;
    unsigned short* srow = &stage[pos * ST_STRIDE];
    for (int kk = 0; kk < 64; ++kk) {
      int k = part + 4 * kk;
      float v = 0.f;
      if (k < 243) { v = img[c][y + i][x + j]; s += v; }
      srow[k] = f2bf(v);
      j += 4;
      if (j >= 9) { j -= 9; if (++c == 3) { c = 0; ++i; } }
    }
    atomicAdd(&meanv[pos], s * (1.f / 243.f));
  }
  __syncthreads();

  f32x4 acc[4][4];
  unsigned linpk[4][4][2];

  // ---- GEMM1: lin = patches @ Ac^T ----
  run_gemm<0>(g_Acswz, stage, w, lane, m, q, acc, linpk);
  __syncthreads();  // patch reads done before overwriting stage with gamma0

  // pack lin (bf16) + gamma0 = ST(lin, lmb[0]) -> stage
#pragma unroll
  for (int un = 0; un < 4; ++un) {
    int f = 64 * w + un * 16 + m;
    float lam = lmbs[f];
#pragma unroll
    for (int t = 0; t < 4; ++t) {
      linpk[t][un][0] = (unsigned)f2bf(acc[t][un][0]) | ((unsigned)f2bf(acc[t][un][1]) << 16);
      linpk[t][un][1] = (unsigned)f2bf(acc[t][un][2]) | ((unsigned)f2bf(acc[t][un][3]) << 16);
#pragma unroll
      for (int r = 0; r < 4; ++r) {
        float x0 = acc[t][un][r];
        float g = x0 - fminf(fmaxf(x0, -lam), lam);  // x - clamp(x,-l,l) == soft-threshold
        stage[(t * 16 + q * 4 + r) * ST_STRIDE + f] = f2bf(g);
      }
    }
  }
  __syncthreads();

  // ---- 11 iterations: gamma <- ST(gamma @ G2 + lin, lmb[kk+1]) ----
  for (int kk = 0; kk < 11; ++kk) {
    run_gemm<1>(g_Gswz, stage, w, lane, m, q, acc, linpk);
    __syncthreads();  // all gamma_k reads done
#pragma unroll
    for (int un = 0; un < 4; ++un) {
      int f = 64 * w + un * 16 + m;
      float lam = lmbs[(kk + 1) * 256 + f];
#pragma unroll
      for (int t = 0; t < 4; ++t)
#pragma unroll
        for (int r = 0; r < 4; ++r) {
          float x0 = acc[t][un][r];
          float g = x0 - fminf(fmaxf(x0, -lam), lam);
          stage[(t * 16 + q * 4 + r) * ST_STRIDE + f] = f2bf(g);
        }
    }
    __syncthreads();  // gamma_{k+1} visible
  }

  // ---- GEMM3: out_cols = gamma @ W3 (+ mean), fold into outacc ----
  run_gemm<0>(g_W3swz, stage, w, lane, m, q, acc, linpk);

#pragma unroll
  for (int un = 0; un < 4; ++un) {
    int cc = 64 * w + un * 16 + m;
    if (cc < 243) {
      int rw = cc / 9, jj = cc - rw * 9;
      int i = rw / 3, c = rw - i * 3;
#pragma unroll
      for (int t = 0; t < 4; ++t)
#pragma unroll
        for (int r = 0; r < 4; ++r) {
          int pos = t * 16 + q * 4 + r;
          int y = (pos >> 3) + i, x = (pos & 7) + jj;
          float val = acc[t][un][r] + meanv[pos];
          atomicAdd(&outacc[c * 256 + y * 16 + x], val);
        }
    }
  }
  __syncthreads();

  float* Ob = out + b * (3 * 128 * 128);
  for (int r = tid; r < 768; r += 256) {
    int c = r >> 8;
    int yx = r & 255;
    int y = yx >> 4, x = yx & 15;
    atomicAdd(&Ob[c * 16384 + (py0 + y) * 128 + (px0 + x)], outacc[r]);
  }
}

// divide by overlap counts
__global__ void div_counts(float* __restrict__ out, int n) {
  int idx = blockIdx.x * 256 + threadIdx.x;
  if (idx >= n) return;
  int x = idx & 127, y = (idx >> 7) & 127;
  int loy = y - 8; if (loy < 0) loy = 0;
  int hiy = y; if (hiy > 119) hiy = 119;
  int lox = x - 8; if (lox < 0) lox = 0;
  int hix = x; if (hix > 119) hix = 119;
  float cnt = (float)((hiy - loy + 1) * (hix - lox + 1));
  out[idx] = out[idx] / cnt;
}

extern "C" void kernel_launch(void* const* d_in, const int* in_sizes, int n_in,
                              void* d_out, int out_size, void* d_ws, size_t ws_size,
                              hipStream_t stream) {
  const float* I = (const float*)d_in[0];
  const float* A = (const float*)d_in[1];
  const float* Dw = (const float*)d_in[2];
  const float* Ww = (const float*)d_in[3];
  const float* lmb = (const float*)d_in[4];
  float* out = (float*)d_out;
  (void)d_ws; (void)ws_size;

  prep_all<<<768, 256, 0, stream>>>(A, Dw, Ww, out);
  lista_fused<<<900, 256, 0, stream>>>(I, lmb, out);
  div_counts<<<768, 256, 0, stream>>>(out, out_size);
}

// Round 5
// 317.322 us; speedup vs baseline: 1.5712x; 1.5712x over previous
//
#include <hip/hip_runtime.h>
#include <stdint.h>

typedef __attribute__((ext_vector_type(8))) short bf16x8;
typedef __attribute__((ext_vector_type(4))) short bf16x4;
typedef __attribute__((ext_vector_type(4))) float f32x4;

__device__ __forceinline__ unsigned short f2bf(float f) {
  union { float f; unsigned u; } v; v.f = f;
  unsigned u = v.u;
  u += 0x7fffu + ((u >> 16) & 1u);
  return (unsigned short)(u >> 16);
}
__device__ __forceinline__ float bfpk_lo(unsigned pk) {
  union { unsigned u; float f; } v; v.u = pk << 16; return v.f;
}
__device__ __forceinline__ float bfpk_hi(unsigned pk) {
  union { unsigned u; float f; } v; v.u = pk & 0xffff0000u; return v.f;
}

// B-fragment swizzle for mfma_f32_16x16x32_bf16:
// element B[k][n] lives at (((k>>5)*16 + (n>>4))*64 + (((k>>3)&3)*16 + (n&15)))*8 + (k&7)
__device__ __forceinline__ int swz_idx(int k, int n) {
  return ((((k >> 5) * 16 + (n >> 4)) * 64) + (((k >> 3) & 3) * 16 + (n & 15))) * 8 + (k & 7);
}

// stage row stride (bf16 elems): 268 -> 134 words == 6 mod 32 -> scalar b16 writes hit
// all 32 banks (<=2-way, free); 8B-aligned b64 reads stay bank-uniform.
#define ST_STRIDE 268

// ---- module-scope scratch; fully rewritten every call ----
__device__ __attribute__((aligned(16))) unsigned short g_Acswz[65536];
__device__ __attribute__((aligned(16))) unsigned short g_Gswz[65536];
__device__ __attribute__((aligned(16))) unsigned short g_W3swz[65536];

// ---------------- fused prep: zero out + build all three swizzled matrices ----------------
__global__ void prep_all(const float* __restrict__ A, const float* __restrict__ Dw,
                         const float* __restrict__ Ww, float* __restrict__ out) {
  __shared__ float red[256];
  const int b = blockIdx.x;
  const int tid = threadIdx.x;
  out[b * 256 + tid] = 0.f;  // 768*256 == out_size exactly

  if (b < 256) {
    float s = 0.f;
    for (int c = tid; c < 243; c += 256) s += A[b * 243 + c];
    red[tid] = s;
    __syncthreads();
    for (int off = 128; off; off >>= 1) {
      if (tid < off) red[tid] += red[tid + off];
      __syncthreads();
    }
    float rm = red[0] * (1.f / 243.f);
    int k = tid;
    float v = 0.f;
    if (k < 243) {
      int rw = k / 9, j = k - rw * 9;
      int i = rw / 3, c = rw - i * 3;
      int corig = c * 81 + i * 9 + j;
      v = A[b * 243 + corig] - rm;
    }
    g_Acswz[swz_idx(k, b)] = f2bf(v);
  } else if (b < 512) {
    int f = b - 256, fp = tid;
    float s = 0.f;
    for (int c = 0; c < 243; ++c) s += A[f * 243 + c] * Dw[c * 256 + fp];
    g_Gswz[swz_idx(fp, f)] = f2bf(((f == fp) ? 1.f : 0.f) - s);
  } else {
    int cc = b - 512, f = tid;
    float v = 0.f;
    if (cc < 243) {
      int rw = cc / 9, j = cc - rw * 9;
      int i = rw / 3, c = rw - i * 3;
      int corig = c * 81 + i * 9 + j;
      v = Ww[corig * 256 + f];
    }
    g_W3swz[swz_idx(f, cc)] = f2bf(v);
  }
}

// ---------------- GEMM with inline global B (prefetch 1 ahead), C-init = 0 ----------------
__device__ __forceinline__ void run_gemm_inline(const unsigned short* __restrict__ Bsrc,
                                                const unsigned short* stg, int w, int lane,
                                                int m, int q, f32x4 (&acc)[4][4]) {
  bf16x8 bcur[4];
#pragma unroll
  for (int un = 0; un < 4; ++un)
    bcur[un] = *(const bf16x8*)(Bsrc + (((4 * w + un) * 64 + lane) << 3));
#pragma unroll
  for (int s = 0; s < 8; ++s) {
    bf16x8 bnext[4];
    if (s < 7) {
#pragma unroll
      for (int un = 0; un < 4; ++un)
        bnext[un] = *(const bf16x8*)(Bsrc + ((((s + 1) * 16 + 4 * w + un) * 64 + lane) << 3));
    }
#pragma unroll
    for (int t = 0; t < 4; ++t) {
      const unsigned short* ap = stg + (t * 16 + m) * ST_STRIDE + s * 32 + q * 8;
      bf16x4 lo = *(const bf16x4*)(ap);
      bf16x4 hi = *(const bf16x4*)(ap + 4);
      bf16x8 afr = __builtin_shufflevector(lo, hi, 0, 1, 2, 3, 4, 5, 6, 7);
#pragma unroll
      for (int un = 0; un < 4; ++un) {
        f32x4 cin = (s == 0) ? (f32x4){0.f, 0.f, 0.f, 0.f} : acc[t][un];
        acc[t][un] = __builtin_amdgcn_mfma_f32_16x16x32_bf16(afr, bcur[un], cin, 0, 0, 0);
      }
    }
    if (s < 7) {
#pragma unroll
      for (int un = 0; un < 4; ++un) bcur[un] = bnext[un];
    }
  }
}

// ---------------- iteration GEMM: B from registers, C-init = lin (packed bf16) ----------------
__device__ __forceinline__ void gemm_regB(const bf16x8 (&bG)[32], const unsigned short* stg,
                                          int m, int q, const unsigned (&linpk)[4][4][2],
                                          f32x4 (&acc)[4][4]) {
#pragma unroll
  for (int s = 0; s < 8; ++s) {
#pragma unroll
    for (int t = 0; t < 4; ++t) {
      const unsigned short* ap = stg + (t * 16 + m) * ST_STRIDE + s * 32 + q * 8;
      bf16x4 lo = *(const bf16x4*)(ap);
      bf16x4 hi = *(const bf16x4*)(ap + 4);
      bf16x8 afr = __builtin_shufflevector(lo, hi, 0, 1, 2, 3, 4, 5, 6, 7);
#pragma unroll
      for (int un = 0; un < 4; ++un) {
        f32x4 cin;
        if (s == 0) {
          cin[0] = bfpk_lo(linpk[t][un][0]);
          cin[1] = bfpk_hi(linpk[t][un][0]);
          cin[2] = bfpk_lo(linpk[t][un][1]);
          cin[3] = bfpk_hi(linpk[t][un][1]);
        } else {
          cin = acc[t][un];
        }
        acc[t][un] = __builtin_amdgcn_mfma_f32_16x16x32_bf16(afr, bG[s * 4 + un], cin, 0, 0, 0);
      }
    }
  }
}

// ---------------- main fused kernel ----------------
// 900 blocks = 4 images * 15*15 tiles of 8x8 positions; 4 waves split 256 features.
// Double-buffered gamma stage -> 1 barrier/iteration; G cached in 128 VGPRs across iters.
__global__ __launch_bounds__(256, 2) void lista_fused(
    const float* __restrict__ I, const float* __restrict__ lmb, float* __restrict__ out) {
  __shared__ __attribute__((aligned(16))) unsigned short stage[2][64 * ST_STRIDE];  // 68.6 KB
  __shared__ float img[3][16][16];
  __shared__ float meanv[64];
  __shared__ float outacc[768];

  const int tid = threadIdx.x;
  const int lane = tid & 63;
  const int w = tid >> 6;
  const int m = lane & 15;
  const int q = lane >> 4;

  const int blk = blockIdx.x;
  const int b = blk / 225;
  const int t2 = blk - b * 225;
  const int ty = t2 / 15;
  const int tx = t2 - ty * 15;
  const int py0 = ty * 8, px0 = tx * 8;

  const float* Ib = I + b * (3 * 128 * 128);
  for (int r = tid; r < 768; r += 256) {
    int c = r >> 8;
    int yx = r & 255;
    int y = yx >> 4, x = yx & 15;
    img[c][y][x] = Ib[c * 16384 + (py0 + y) * 128 + (px0 + x)];
    outacc[r] = 0.f;
  }
  if (tid < 64) meanv[tid] = 0.f;
  __syncthreads();

  // ---- build patch stage (k-order k=(i*3+c)*9+j) into stage[0] + per-position means ----
  {
    const int pos = tid & 63;
    const int part = tid >> 6;
    const int y = pos >> 3, x = pos & 7;
    int j = part, c = 0, i = 0;
    float s = 0.f;
    unsigned short* srow = &stage[0][pos * ST_STRIDE];
    for (int kk = 0; kk < 64; ++kk) {
      int k = part + 4 * kk;
      float v = 0.f;
      if (k < 243) { v = img[c][y + i][x + j]; s += v; }
      srow[k] = f2bf(v);
      j += 4;
      if (j >= 9) { j -= 9; if (++c == 3) { c = 0; ++i; } }
    }
    atomicAdd(&meanv[pos], s * (1.f / 243.f));
  }

  // ---- load wave's G-slice into registers (overlaps with other waves' build) ----
  bf16x8 bG[32];
#pragma unroll
  for (int s = 0; s < 8; ++s)
#pragma unroll
    for (int un = 0; un < 4; ++un)
      bG[s * 4 + un] = *(const bf16x8*)(g_Gswz + (((s * 16 + 4 * w + un) * 64 + lane) << 3));

  __syncthreads();

  f32x4 acc[4][4];
  unsigned linpk[4][4][2];

  // ---- GEMM1: lin = patches @ Ac^T ----
  run_gemm_inline(g_Acswz, stage[0], w, lane, m, q, acc);

  // pack lin (bf16) + gamma0 = ST(lin, lmb[0]) -> stage[1] (patch readers unaffected)
#pragma unroll
  for (int un = 0; un < 4; ++un) {
    int f = 64 * w + un * 16 + m;
    float lam = lmb[f];
#pragma unroll
    for (int t = 0; t < 4; ++t) {
      linpk[t][un][0] = (unsigned)f2bf(acc[t][un][0]) | ((unsigned)f2bf(acc[t][un][1]) << 16);
      linpk[t][un][1] = (unsigned)f2bf(acc[t][un][2]) | ((unsigned)f2bf(acc[t][un][3]) << 16);
#pragma unroll
      for (int r = 0; r < 4; ++r) {
        float x0 = acc[t][un][r];
        float g = x0 - fminf(fmaxf(x0, -lam), lam);  // soft-threshold
        stage[1][(t * 16 + q * 4 + r) * ST_STRIDE + f] = f2bf(g);
      }
    }
  }
  __syncthreads();

  // ---- 11 iterations: gamma <- ST(gamma @ G2 + lin, lmb[kk+1]); buffers alternate ----
  for (int kk = 0; kk < 11; ++kk) {
    const int rb = (kk & 1) ^ 1;  // kk even: read stage[1], write stage[0]
    gemm_regB(bG, stage[rb], m, q, linpk, acc);
#pragma unroll
    for (int un = 0; un < 4; ++un) {
      int f = 64 * w + un * 16 + m;
      float lam = lmb[(kk + 1) * 256 + f];
#pragma unroll
      for (int t = 0; t < 4; ++t)
#pragma unroll
        for (int r = 0; r < 4; ++r) {
          float x0 = acc[t][un][r];
          float g = x0 - fminf(fmaxf(x0, -lam), lam);
          stage[rb ^ 1][(t * 16 + q * 4 + r) * ST_STRIDE + f] = f2bf(g);
        }
    }
    __syncthreads();
  }

  // ---- GEMM3: out_cols = gamma_11 (stage[0]) @ W3 (+ mean), fold into outacc ----
  run_gemm_inline(g_W3swz, stage[0], w, lane, m, q, acc);

#pragma unroll
  for (int un = 0; un < 4; ++un) {
    int cc = 64 * w + un * 16 + m;
    if (cc < 243) {
      int rw = cc / 9, jj = cc - rw * 9;
      int i = rw / 3, c = rw - i * 3;
#pragma unroll
      for (int t = 0; t < 4; ++t)
#pragma unroll
        for (int r = 0; r < 4; ++r) {
          int pos = t * 16 + q * 4 + r;
          int y = (pos >> 3) + i, x = (pos & 7) + jj;
          float val = acc[t][un][r] + meanv[pos];
          atomicAdd(&outacc[c * 256 + y * 16 + x], val);
        }
    }
  }
  __syncthreads();

  float* Ob = out + b * (3 * 128 * 128);
  for (int r = tid; r < 768; r += 256) {
    int c = r >> 8;
    int yx = r & 255;
    int y = yx >> 4, x = yx & 15;
    atomicAdd(&Ob[c * 16384 + (py0 + y) * 128 + (px0 + x)], outacc[r]);
  }
}

// divide by overlap counts
__global__ void div_counts(float* __restrict__ out, int n) {
  int idx = blockIdx.x * 256 + threadIdx.x;
  if (idx >= n) return;
  int x = idx & 127, y = (idx >> 7) & 127;
  int loy = y - 8; if (loy < 0) loy = 0;
  int hiy = y; if (hiy > 119) hiy = 119;
  int lox = x - 8; if (lox < 0) lox = 0;
  int hix = x; if (hix > 119) hix = 119;
  float cnt = (float)((hiy - loy + 1) * (hix - lox + 1));
  out[idx] = out[idx] / cnt;
}

extern "C" void kernel_launch(void* const* d_in, const int* in_sizes, int n_in,
                              void* d_out, int out_size, void* d_ws, size_t ws_size,
                              hipStream_t stream) {
  const float* I = (const float*)d_in[0];
  const float* A = (const float*)d_in[1];
  const float* Dw = (const float*)d_in[2];
  const float* Ww = (const float*)d_in[3];
  const float* lmb = (const float*)d_in[4];
  float* out = (float*)d_out;
  (void)d_ws; (void)ws_size;

  prep_all<<<768, 256, 0, stream>>>(A, Dw, Ww, out);
  lista_fused<<<900, 256, 0, stream>>>(I, lmb, out);
  div_counts<<<768, 256, 0, stream>>>(out, out_size);
}

// Round 6
// 278.597 us; speedup vs baseline: 1.7896x; 1.1390x over previous
//
#include <hip/hip_runtime.h>
#include <stdint.h>

typedef __attribute__((ext_vector_type(8))) short bf16x8;
typedef __attribute__((ext_vector_type(4))) float f32x4;

__device__ __forceinline__ unsigned short f2bf(float f) {
  union { float f; unsigned u; } v; v.f = f;
  unsigned u = v.u;
  u += 0x7fffu + ((u >> 16) & 1u);
  return (unsigned short)(u >> 16);
}
__device__ __forceinline__ float bfpk_lo(unsigned pk) {
  union { unsigned u; float f; } v; v.u = pk << 16; return v.f;
}
__device__ __forceinline__ float bfpk_hi(unsigned pk) {
  union { unsigned u; float f; } v; v.u = pk & 0xffff0000u; return v.f;
}

// B-fragment swizzle for mfma_f32_16x16x32_bf16:
// element B[k][n] lives at (((k>>5)*16 + (n>>4))*64 + (((k>>3)&3)*16 + (n&15)))*8 + (k&7)
__device__ __forceinline__ int swz_idx(int k, int n) {
  return ((((k >> 5) * 16 + (n >> 4)) * 64) + (((k >> 3) & 3) * 16 + (n & 15))) * 8 + (k & 7);
}

// stage row stride (bf16 elems): 272 -> rows 16B-aligned => A-frag = one ds_read_b128
// (bank-uniform: 8 words/bank exactly). Scalar b16 gamma-writes: banks 8*(m%4)+4q+m/2
// cover all 32 banks <=2-way (free). 272 words==8 mod 32 keeps spread.
#define ST_STRIDE 272

// ---- module-scope scratch; fully rewritten every call ----
__device__ __attribute__((aligned(16))) unsigned short g_Acswz[65536];
__device__ __attribute__((aligned(16))) unsigned short g_Gswz[65536];
__device__ __attribute__((aligned(16))) unsigned short g_W3swz[65536];

// ---------------- fused prep: zero out + build all three swizzled matrices ----------------
__global__ void prep_all(const float* __restrict__ A, const float* __restrict__ Dw,
                         const float* __restrict__ Ww, float* __restrict__ out) {
  __shared__ float red[256];
  const int b = blockIdx.x;
  const int tid = threadIdx.x;
  out[b * 256 + tid] = 0.f;  // 768*256 == out_size exactly

  if (b < 256) {
    float s = 0.f;
    for (int c = tid; c < 243; c += 256) s += A[b * 243 + c];
    red[tid] = s;
    __syncthreads();
    for (int off = 128; off; off >>= 1) {
      if (tid < off) red[tid] += red[tid + off];
      __syncthreads();
    }
    float rm = red[0] * (1.f / 243.f);
    int k = tid;
    float v = 0.f;
    if (k < 243) {
      int rw = k / 9, j = k - rw * 9;
      int i = rw / 3, c = rw - i * 3;
      int corig = c * 81 + i * 9 + j;
      v = A[b * 243 + corig] - rm;
    }
    g_Acswz[swz_idx(k, b)] = f2bf(v);
  } else if (b < 512) {
    int f = b - 256, fp = tid;
    float s = 0.f;
    for (int c = 0; c < 243; ++c) s += A[f * 243 + c] * Dw[c * 256 + fp];
    g_Gswz[swz_idx(fp, f)] = f2bf(((f == fp) ? 1.f : 0.f) - s);
  } else {
    int cc = b - 512, f = tid;
    float v = 0.f;
    if (cc < 243) {
      int rw = cc / 9, j = cc - rw * 9;
      int i = rw / 3, c = rw - i * 3;
      int corig = c * 81 + i * 9 + j;
      v = Ww[corig * 256 + f];
    }
    g_W3swz[swz_idx(f, cc)] = f2bf(v);
  }
}

// ------- GEMM core: acc[t][un] = stage(64x256) @ Bslice + C. B streamed (1-ahead prefetch).
// CMODE 0: C-init = 0; CMODE 1: C-init = unpacked bf16 lin.
template <int CMODE>
__device__ __forceinline__ void run_gemm(const unsigned short* __restrict__ Bsrc,
                                         const unsigned short* stg, int w, int lane,
                                         int m, int q, f32x4 (&acc)[4][4],
                                         const unsigned (&linpk)[4][4][2]) {
  bf16x8 bcur[4];
#pragma unroll
  for (int un = 0; un < 4; ++un)
    bcur[un] = *(const bf16x8*)(Bsrc + (((4 * w + un) * 64 + lane) << 3));
#pragma unroll
  for (int s = 0; s < 8; ++s) {
    bf16x8 bnext[4];
    if (s < 7) {
#pragma unroll
      for (int un = 0; un < 4; ++un)
        bnext[un] = *(const bf16x8*)(Bsrc + ((((s + 1) * 16 + 4 * w + un) * 64 + lane) << 3));
    }
#pragma unroll
    for (int t = 0; t < 4; ++t) {
      bf16x8 afr = *(const bf16x8*)(stg + (t * 16 + m) * ST_STRIDE + s * 32 + q * 8);
#pragma unroll
      for (int un = 0; un < 4; ++un) {
        f32x4 cin;
        if (s == 0) {
          if (CMODE == 1) {
            cin[0] = bfpk_lo(linpk[t][un][0]);
            cin[1] = bfpk_hi(linpk[t][un][0]);
            cin[2] = bfpk_lo(linpk[t][un][1]);
            cin[3] = bfpk_hi(linpk[t][un][1]);
          } else {
            cin = (f32x4){0.f, 0.f, 0.f, 0.f};
          }
        } else {
          cin = acc[t][un];
        }
        acc[t][un] = __builtin_amdgcn_mfma_f32_16x16x32_bf16(afr, bcur[un], cin, 0, 0, 0);
      }
    }
    if (s < 7) {
#pragma unroll
      for (int un = 0; un < 4; ++un) bcur[un] = bnext[un];
    }
  }
}

// ---------------- main fused kernel ----------------
// 900 blocks = 4 images * 15*15 tiles of 8x8 positions; 4 waves split 256 features.
// Double-buffered gamma stage -> 1 barrier/iteration. B streamed from L2 (no reg caching:
// acc64+linpk32+transients fits 256-reg budget; bG[32] caching spilled — rounds 4/5).
__global__ __launch_bounds__(256, 2) void lista_fused(
    const float* __restrict__ I, const float* __restrict__ lmb, float* __restrict__ out) {
  __shared__ __attribute__((aligned(16))) unsigned short stage[2][64 * ST_STRIDE];  // 69.6 KB
  __shared__ float img[3][16][16];
  __shared__ float meanv[64];
  __shared__ float outacc[768];

  const int tid = threadIdx.x;
  const int lane = tid & 63;
  const int w = tid >> 6;
  const int m = lane & 15;
  const int q = lane >> 4;

  const int blk = blockIdx.x;
  const int b = blk / 225;
  const int t2 = blk - b * 225;
  const int ty = t2 / 15;
  const int tx = t2 - ty * 15;
  const int py0 = ty * 8, px0 = tx * 8;

  const float* Ib = I + b * (3 * 128 * 128);
  for (int r = tid; r < 768; r += 256) {
    int c = r >> 8;
    int yx = r & 255;
    int y = yx >> 4, x = yx & 15;
    img[c][y][x] = Ib[c * 16384 + (py0 + y) * 128 + (px0 + x)];
    outacc[r] = 0.f;
  }
  if (tid < 64) meanv[tid] = 0.f;
  __syncthreads();

  // ---- build patch stage (k-order k=(i*3+c)*9+j) into stage[0] + per-position means ----
  {
    const int pos = tid & 63;
    const int part = tid >> 6;
    const int y = pos >> 3, x = pos & 7;
    int j = part, c = 0, i = 0;
    float s = 0.f;
    unsigned short* srow = &stage[0][pos * ST_STRIDE];
    for (int kk = 0; kk < 64; ++kk) {
      int k = part + 4 * kk;
      float v = 0.f;
      if (k < 243) { v = img[c][y + i][x + j]; s += v; }
      srow[k] = f2bf(v);
      j += 4;
      if (j >= 9) { j -= 9; if (++c == 3) { c = 0; ++i; } }
    }
    atomicAdd(&meanv[pos], s * (1.f / 243.f));
  }
  __syncthreads();

  f32x4 acc[4][4];
  unsigned linpk[4][4][2];

  // ---- GEMM1: lin = patches @ Ac^T ----
  run_gemm<0>(g_Acswz, stage[0], w, lane, m, q, acc, linpk);

  // pack lin (bf16) + gamma0 = ST(lin, lmb[0]) -> stage[1] (patch stage[0] untouched)
#pragma unroll
  for (int un = 0; un < 4; ++un) {
    int f = 64 * w + un * 16 + m;
    float lam = lmb[f];
#pragma unroll
    for (int t = 0; t < 4; ++t) {
      linpk[t][un][0] = (unsigned)f2bf(acc[t][un][0]) | ((unsigned)f2bf(acc[t][un][1]) << 16);
      linpk[t][un][1] = (unsigned)f2bf(acc[t][un][2]) | ((unsigned)f2bf(acc[t][un][3]) << 16);
#pragma unroll
      for (int r = 0; r < 4; ++r) {
        float x0 = acc[t][un][r];
        float g = x0 - fminf(fmaxf(x0, -lam), lam);  // soft-threshold
        stage[1][(t * 16 + q * 4 + r) * ST_STRIDE + f] = f2bf(g);
      }
    }
  }
  __syncthreads();

  // ---- 11 iterations: gamma <- ST(gamma @ G2 + lin, lmb[kk+1]); buffers alternate ----
  for (int kk = 0; kk < 11; ++kk) {
    const int rb = (kk & 1) ^ 1;  // kk even: read stage[1], write stage[0]
    run_gemm<1>(g_Gswz, stage[rb], w, lane, m, q, acc, linpk);
#pragma unroll
    for (int un = 0; un < 4; ++un) {
      int f = 64 * w + un * 16 + m;
      float lam = lmb[(kk + 1) * 256 + f];
#pragma unroll
      for (int t = 0; t < 4; ++t)
#pragma unroll
        for (int r = 0; r < 4; ++r) {
          float x0 = acc[t][un][r];
          float g = x0 - fminf(fmaxf(x0, -lam), lam);
          stage[rb ^ 1][(t * 16 + q * 4 + r) * ST_STRIDE + f] = f2bf(g);
        }
    }
    __syncthreads();
  }

  // ---- GEMM3: out_cols = gamma_11 (stage[0]) @ W3 (+ mean), fold into outacc ----
  run_gemm<0>(g_W3swz, stage[0], w, lane, m, q, acc, linpk);

#pragma unroll
  for (int un = 0; un < 4; ++un) {
    int cc = 64 * w + un * 16 + m;
    if (cc < 243) {
      int rw = cc / 9, jj = cc - rw * 9;
      int i = rw / 3, c = rw - i * 3;
#pragma unroll
      for (int t = 0; t < 4; ++t)
#pragma unroll
        for (int r = 0; r < 4; ++r) {
          int pos = t * 16 + q * 4 + r;
          int y = (pos >> 3) + i, x = (pos & 7) + jj;
          float val = acc[t][un][r] + meanv[pos];
          atomicAdd(&outacc[c * 256 + y * 16 + x], val);
        }
    }
  }
  __syncthreads();

  float* Ob = out + b * (3 * 128 * 128);
  for (int r = tid; r < 768; r += 256) {
    int c = r >> 8;
    int yx = r & 255;
    int y = yx >> 4, x = yx & 15;
    atomicAdd(&Ob[c * 16384 + (py0 + y) * 128 + (px0 + x)], outacc[r]);
  }
}

// divide by overlap counts
__global__ void div_counts(float* __restrict__ out, int n) {
  int idx = blockIdx.x * 256 + threadIdx.x;
  if (idx >= n) return;
  int x = idx & 127, y = (idx >> 7) & 127;
  int loy = y - 8; if (loy < 0) loy = 0;
  int hiy = y; if (hiy > 119) hiy = 119;
  int lox = x - 8; if (lox < 0) lox = 0;
  int hix = x; if (hix > 119) hix = 119;
  float cnt = (float)((hiy - loy + 1) * (hix - lox + 1));
  out[idx] = out[idx] / cnt;
}

extern "C" void kernel_launch(void* const* d_in, const int* in_sizes, int n_in,
                              void* d_out, int out_size, void* d_ws, size_t ws_size,
                              hipStream_t stream) {
  const float* I = (const float*)d_in[0];
  const float* A = (const float*)d_in[1];
  const float* Dw = (const float*)d_in[2];
  const float* Ww = (const float*)d_in[3];
  const float* lmb = (const float*)d_in[4];
  float* out = (float*)d_out;
  (void)d_ws; (void)ws_size;

  prep_all<<<768, 256, 0, stream>>>(A, Dw, Ww, out);
  lista_fused<<<900, 256, 0, stream>>>(I, lmb, out);
  div_counts<<<768, 256, 0, stream>>>(out, out_size);
}